// Round 9
// baseline (13162.837 us; speedup 1.0000x reference)
//
#include <hip/hip_runtime.h>
#include <math.h>

#define HID 512
#define B 64
#define SEQT 1024
#define FUT 16
#define TT (SEQT + FUT)
#define NWG 256
#define TPB 512          // fallback path block size
#define TPB1 1024        // main kernel block size (16 waves, 4/SIMD)
#define NWAVE1 16
#define JPW 2            // hidden units owned per WG = HID/NWG
#define HB (HID * B)     // one h buffer, floats
#define BLOBF 12288      // floats per WG: 4096 (phase1) + 8192 (phase2)

typedef __attribute__((ext_vector_type(2))) float f2;   // v_pk_fma_f32 pairs

// ws float layout (main path):
//   [0..511]               barrier block (ints): slot[wg] at int wg (wg<256)
//   [512 .. +2HB)          h1 double buffer  (float4 tiles: h4[k>>2][b][k&3])
//   [.. +2HB)              h2 double buffer  (same layout)
//   [.. +NWG*BLOBF)        rearranged weight blobs (per WG)
//   [.. +SEQT*B)           xT (x transposed to [t][b])
//   [.. +SEQT*NWG*B)       deferred-output partials part[t][wg][b] (defer mode)
#define WS_H1_F   512
#define WS_H2_F   (WS_H1_F + 2 * HB)
#define WS_BLOB_F (WS_H2_F + 2 * HB)
#define WS_XT_F   (WS_BLOB_F + NWG * BLOBF)
#define WS_TOT_F  (WS_XT_F + SEQT * B)
#define WS_PART_F WS_TOT_F
#define WS_TOT2_F (WS_PART_F + (size_t)SEQT * NWG * B)

// publish device-wide WITHOUT buffer_wbl2 (r6 win: wbl2 writeback pushed h
// past the MALL -> every post-barrier read paid HBM latency).
__device__ inline void pub_store(float* p, float v) {
  __hip_atomic_store(p, v, __ATOMIC_RELAXED, __HIP_MEMORY_SCOPE_AGENT);
}

// ---- grid barrier v5: slot stores + EVERY WG polls all slots directly ------
// Rules from r2-r8: no RMW arrivals; relaxed spin loads (acquire-per-poll =
// buffer_inv per poll = L2 dead); ONE pre-spin acquire fence (inv) per WG.
__device__ inline void gbar5(int* bb, int wg, int bar) {
  __builtin_amdgcn_s_waitcnt(0);   // all waves: drain own write-through stores
  __syncthreads();
  const int tid = threadIdx.x;
  if (tid == 0) {
    __hip_atomic_store(bb + wg, bar, __ATOMIC_RELAXED, __HIP_MEMORY_SCOPE_AGENT);
    __builtin_amdgcn_fence(__ATOMIC_ACQUIRE, "agent");  // pre-spin inv, once
  }
  if (tid < 64) {                  // wave 0: poll all 256 arrival slots
    for (;;) {
      int a = __hip_atomic_load(bb + tid,       __ATOMIC_RELAXED, __HIP_MEMORY_SCOPE_AGENT);
      int b = __hip_atomic_load(bb + 64  + tid, __ATOMIC_RELAXED, __HIP_MEMORY_SCOPE_AGENT);
      int c = __hip_atomic_load(bb + 128 + tid, __ATOMIC_RELAXED, __HIP_MEMORY_SCOPE_AGENT);
      int d = __hip_atomic_load(bb + 192 + tid, __ATOMIC_RELAXED, __HIP_MEMORY_SCOPE_AGENT);
      if (__all(a >= bar && b >= bar && c >= bar && d >= bar)) break;
      __builtin_amdgcn_s_sleep(1);
    }
  }
  __syncthreads();  // h loads below stay below
}

// ---------------- prep: zero state, rearrange weights, transpose x -----------
__global__ void __launch_bounds__(256) prep_ws(
    const float* __restrict__ x,
    const float* __restrict__ U1, const float* __restrict__ W2,
    const float* __restrict__ U2, float* __restrict__ ws)
{
  const int idx = blockIdx.x * blockDim.x + threadIdx.x;
  if (idx < WS_BLOB_F) {                       // barrier block + h buffers
    ws[idx] = 0.0f;
  }
  {
    const int i2 = idx - WS_BLOB_F;
    if (i2 >= 0 && i2 < NWG * BLOBF) {
      const int wg  = i2 / BLOBF;
      const int off = i2 - wg * BLOBF;
      const int j0  = wg * JPW;
      float v;
      if (off < 4096) {                        // phase1: [k*8 + r] = U1[row(r)][k]
        const int k = off >> 3, r = off & 7;
        const int row = (r >> 1) * HID + j0 + (r & 1);
        v = U1[(size_t)row * HID + k];
      } else {                                 // phase2: [k*16 + rr]
        const int o2 = off - 4096;
        const int k = o2 >> 4, rr = o2 & 15;
        const int r = rr & 7;
        const int row = (r >> 1) * HID + j0 + (r & 1);
        v = (rr < 8) ? W2[(size_t)row * HID + k] : U2[(size_t)row * HID + k];
      }
      ws[WS_BLOB_F + i2] = v;
    }
  }
  {
    const int i3 = idx - WS_XT_F;
    if (i3 >= 0 && i3 < SEQT * B) {
      const int t = i3 >> 6, b = i3 & 63;
      ws[WS_XT_F + i3] = x[(size_t)b * SEQT + t];
    }
  }
}

// -------- persistent 2-layer LSTM: LDS weights, register-carried h1 ----------
// r9: packed-fp32 dot products (v_pk_fma_f32) + two-stage cell reductions
// (stage1: 8 waves sum 16 wave-partials -> gsum; stage2: 128-thread cell).
__global__ void __launch_bounds__(TPB1, 1) rnn_main(
    const float* __restrict__ W1, const float* __restrict__ bW1,
    const float* __restrict__ bU1,
    const float* __restrict__ bW2, const float* __restrict__ bU2,
    const float* __restrict__ lw, const float* __restrict__ lb,
    float* __restrict__ out,
    int* __restrict__ bb,
    float* __restrict__ h1b, float* __restrict__ h2b,
    const float* __restrict__ wbl, const float* __restrict__ xT,
    float* __restrict__ part, int defer)
{
  __shared__ float wlds[BLOBF];         // 48 KB persistent weight blob
  __shared__ float red[NWAVE1][8][B];   // per-wave partial dots, 32 KB
  __shared__ float gsum[8][B];          // stage-1 reduced gates, 2 KB
  __shared__ float outred[NWAVE1][B];   // output-head reduction, 4 KB
  __shared__ float c1s[JPW][B], c2s[JPW][B];
  __shared__ float pout[JPW][B];        // per-step output partial staging
  __shared__ float w1c[8], bs1[8], bs2[8], lwc[JPW];

  const int wg   = blockIdx.x;
  const int j0   = wg * JPW;
  const int tid  = threadIdx.x;
  const int lane = tid & 63;
  const int wvu  = __builtin_amdgcn_readfirstlane(tid >> 6);

  // ---- one-time: copy this WG's weight blob into LDS ----
  {
    const float4* gsrc = (const float4*)(wbl + (size_t)wg * BLOBF);
    float4* ldst = (float4*)wlds;
    #pragma unroll
    for (int i = 0; i < BLOBF / 4 / TPB1; ++i)
      ldst[i * TPB1 + tid] = gsrc[i * TPB1 + tid];
  }
  if (tid < JPW * B) { c1s[tid >> 6][lane] = 0.f; c2s[tid >> 6][lane] = 0.f; }
  if (tid < 8) {
    const int g = tid >> 1, jl = tid & 1;
    const int row = g * HID + j0 + jl;
    w1c[tid] = W1[row];
    bs1[tid] = bW1[row] + bU1[row];
    bs2[tid] = bW2[row] + bU2[row];
  }
  if (tid < JPW) lwc[tid] = lw[j0 + tid];
  __syncthreads();

  const float* wl1 = wlds + wvu * 256;          // phase1 weights, this wave
  const float* wl2 = wlds + 4096 + wvu * 512;   // phase2 weights, this wave
  const float lbv = lb[0];

  float4 H1[8], Q[8];                           // h1 carry + h2old staging
  #pragma unroll
  for (int i = 0; i < 8; ++i) H1[i] = make_float4(0.f, 0.f, 0.f, 0.f);

  int bar = 0;
  for (int t = 0; t < TT; ++t) {
    float*       h1new = h1b + (t & 1) * HB;
    const float* h2old = h2b + ((t + 1) & 1) * HB;
    float*       h2new = h2b + (t & 1) * HB;

    // prefetch x for cell-1 (teacher region)
    float xvpref = 0.f;
    if (tid < JPW * B && t < SEQT) xvpref = xT[(size_t)t * B + lane];

    // -------- phase 1: gates1 = U1 h1(t-1), h1(t-1) in H1 registers ---------
    // packed fp32: 4 float2 accumulators over adjacent gate rows
    {
      f2 a01 = {0.f, 0.f}, a23 = {0.f, 0.f}, a45 = {0.f, 0.f}, a67 = {0.f, 0.f};
      #pragma unroll
      for (int c = 0; c < 8; ++c) {             // 8 k-quads in this wave's 32-k
        const float hh[4] = {H1[c].x, H1[c].y, H1[c].z, H1[c].w};
        #pragma unroll
        for (int j = 0; j < 4; ++j) {
          const f2* wp = (const f2*)(wl1 + c * 32 + j * 8);
          const f2 hs = {hh[j], hh[j]};
          a01 = __builtin_elementwise_fma(wp[0], hs, a01);
          a23 = __builtin_elementwise_fma(wp[1], hs, a23);
          a45 = __builtin_elementwise_fma(wp[2], hs, a45);
          a67 = __builtin_elementwise_fma(wp[3], hs, a67);
        }
      }
      red[wvu][0][lane] = a01.x; red[wvu][1][lane] = a01.y;
      red[wvu][2][lane] = a23.x; red[wvu][3][lane] = a23.y;
      red[wvu][4][lane] = a45.x; red[wvu][5][lane] = a45.y;
      red[wvu][6][lane] = a67.x; red[wvu][7][lane] = a67.y;
    }
    __syncthreads();

    // stage-1 reduction: 8 waves sum the 16 wave-partials -> gsum[r][b]
    if (tid < 8 * B) {
      const int r = tid >> 6, b = lane;
      float s = 0.f;
      #pragma unroll
      for (int w = 0; w < NWAVE1; ++w) s += red[w][r][b];
      gsum[r][b] = s;
    }
    __syncthreads();

    // cell-1 elementwise (2 j's x 64 b = 128 threads)
    if (tid < JPW * B) {
      const int jl = tid >> 6, b = tid & 63;
      const float xv = (t < SEQT) ? xvpref : out[(size_t)b * TT + (t - 1)];
      float gate[4];
      #pragma unroll
      for (int g = 0; g < 4; ++g)
        gate[g] = bs1[g * 2 + jl] + xv * w1c[g * 2 + jl] + gsum[g * 2 + jl][b];
      const float c = gate[1] * c1s[jl][b] + gate[0] * gate[2];
      c1s[jl][b] = c;
      const int j = j0 + jl;
      pub_store(&h1new[(size_t)(j >> 2) * (B * 4) + b * 4 + (j & 3)],
                gate[3] * tanhf(c));
    }

    ++bar;
    gbar5(bb, wg, bar);

    // non-defer mode only: duty WG computes output head inline (r7 behavior).
    if (!defer && wg == (t & 127) && t >= 1 && t <= SEQT - 1) {
      const float4* hb2 = (const float4*)h2old + (size_t)(wvu * 8) * B + lane;
      const float4* lw4 = (const float4*)lw + wvu * 8;
      float p = 0.f;
      #pragma unroll
      for (int i = 0; i < 8; ++i) {
        const float4 hv = hb2[i * B];
        const float4 wv = lw4[i];
        p = fmaf(wv.x, hv.x, p); p = fmaf(wv.y, hv.y, p);
        p = fmaf(wv.z, hv.z, p); p = fmaf(wv.w, hv.w, p);
      }
      outred[wvu][lane] = p;
      __syncthreads();
      if (tid < B) {
        float o = lbv;
        #pragma unroll
        for (int s = 0; s < NWAVE1; ++s) o += outred[s][tid];
        pub_store(&out[(size_t)tid * TT + (t - 1)], o);
      }
      __syncthreads();
    }

    // -------- phase 2: gates2 = W2 h1(t) + U2 h2(t-1) ------------------------
    // H1 <- h1(t) (kept for next step's phase 1), Q <- h2(t-1)
    {
      const float4* pp4 = (const float4*)h1new + (size_t)(wvu * 8) * B + lane;
      const float4* qq4 = (const float4*)h2old + (size_t)(wvu * 8) * B + lane;
      #pragma unroll
      for (int i = 0; i < 8; ++i) H1[i] = pp4[i * B];
      #pragma unroll
      for (int i = 0; i < 8; ++i) Q[i] = qq4[i * B];
      f2 a01 = {0.f, 0.f}, a23 = {0.f, 0.f}, a45 = {0.f, 0.f}, a67 = {0.f, 0.f};
      #pragma unroll
      for (int c = 0; c < 8; ++c) {
        const float hp_[4] = {H1[c].x, H1[c].y, H1[c].z, H1[c].w};
        const float hq_[4] = {Q[c].x, Q[c].y, Q[c].z, Q[c].w};
        #pragma unroll
        for (int j = 0; j < 4; ++j) {
          const f2* wp = (const f2*)(wl2 + c * 64 + j * 16);
          const f2 hs1 = {hp_[j], hp_[j]};
          const f2 hs2 = {hq_[j], hq_[j]};
          a01 = __builtin_elementwise_fma(wp[0], hs1, a01);
          a23 = __builtin_elementwise_fma(wp[1], hs1, a23);
          a45 = __builtin_elementwise_fma(wp[2], hs1, a45);
          a67 = __builtin_elementwise_fma(wp[3], hs1, a67);
          a01 = __builtin_elementwise_fma(wp[4], hs2, a01);
          a23 = __builtin_elementwise_fma(wp[5], hs2, a23);
          a45 = __builtin_elementwise_fma(wp[6], hs2, a45);
          a67 = __builtin_elementwise_fma(wp[7], hs2, a67);
        }
      }
      red[wvu][0][lane] = a01.x; red[wvu][1][lane] = a01.y;
      red[wvu][2][lane] = a23.x; red[wvu][3][lane] = a23.y;
      red[wvu][4][lane] = a45.x; red[wvu][5][lane] = a45.y;
      red[wvu][6][lane] = a67.x; red[wvu][7][lane] = a67.y;
    }
    __syncthreads();

    // stage-1 reduction for cell-2
    if (tid < 8 * B) {
      const int r = tid >> 6, b = lane;
      float s = 0.f;
      #pragma unroll
      for (int w = 0; w < NWAVE1; ++w) s += red[w][r][b];
      gsum[r][b] = s;
    }
    __syncthreads();

    // cell-2 elementwise
    if (tid < JPW * B) {
      const int jl = tid >> 6, b = tid & 63;
      float gate[4];
      #pragma unroll
      for (int g = 0; g < 4; ++g)
        gate[g] = bs2[g * 2 + jl] + gsum[g * 2 + jl][b];
      const float c = gate[1] * c2s[jl][b] + gate[0] * gate[2];
      c2s[jl][b] = c;
      const float h2v = gate[3] * tanhf(c);
      const int j = j0 + jl;
      pub_store(&h2new[(size_t)(j >> 2) * (B * 4) + b * 4 + (j & 3)], h2v);
      if (defer && t < SEQT) pout[jl][b] = lwc[jl] * h2v;  // output partial
    }
    __syncthreads();  // protect red[]/gsum + publish pout

    // deferred-output partial store: 64 floats/WG/step, write-through
    if (defer && t < SEQT && tid < B) {
      pub_store(&part[((size_t)t * NWG + wg) * B + tid],
                pout[0][tid] + pout[1][tid]);
    }

    // Autoregressive region: out(t) must be globally visible before phase1(t+1)
    if (t >= SEQT - 1) {
      ++bar;
      gbar5(bb, wg, bar);
      if (wg == 0) {
        const float4* hb2 = (const float4*)h2new + (size_t)(wvu * 8) * B + lane;
        const float4* lw4 = (const float4*)lw + wvu * 8;
        float p = 0.f;
        #pragma unroll
        for (int i = 0; i < 8; ++i) {
          const float4 hv = hb2[i * B];
          const float4 wv = lw4[i];
          p = fmaf(wv.x, hv.x, p); p = fmaf(wv.y, hv.y, p);
          p = fmaf(wv.z, hv.z, p); p = fmaf(wv.w, hv.w, p);
        }
        outred[wvu][lane] = p;
        __syncthreads();
        if (tid < B) {
          float o = lbv;
          #pragma unroll
          for (int s = 0; s < NWAVE1; ++s) o += outred[s][tid];
          pub_store(&out[(size_t)tid * TT + t], o);
        }
        __syncthreads();
      }
      ++bar;
      gbar5(bb, wg, bar);
    }
  }

  // ---- defer mode tail: parallel reduction of output partials (t=0..1022) --
  if (defer) {
    ++bar;
    gbar5(bb, wg, bar);   // all partial stores visible + L2 inv'd
    for (int tt = wg; tt < SEQT - 1; tt += NWG) {
      const float* pp = part + ((size_t)tt * NWG + wvu * 16) * B + lane;
      float s = 0.f;
      #pragma unroll
      for (int i = 0; i < 16; ++i) s += pp[i * B];
      outred[wvu][lane] = s;
      __syncthreads();
      if (tid < B) {
        float o = lbv;
        #pragma unroll
        for (int v = 0; v < NWAVE1; ++v) o += outred[v][tid];
        out[(size_t)tid * TT + tt] = o;
      }
      __syncthreads();
    }
  }
}

// =================== fallback path (round-0 kernel, known correct) ===========
__device__ inline void gbar(int* cnt, int target) {
  __syncthreads();
  if (threadIdx.x == 0) {
    __threadfence();
    __hip_atomic_fetch_add(cnt, 1, __ATOMIC_RELEASE, __HIP_MEMORY_SCOPE_AGENT);
    while (__hip_atomic_load(cnt, __ATOMIC_ACQUIRE, __HIP_MEMORY_SCOPE_AGENT) < target) {
      __builtin_amdgcn_s_sleep(2);
    }
  }
  __syncthreads();
}

__global__ void __launch_bounds__(TPB) zero_ws(float* ws, int n) {
  int i = blockIdx.x * blockDim.x + threadIdx.x;
  if (i < n) ws[i] = 0.0f;
}

__global__ void __launch_bounds__(TPB) rnn_fallback(
    const float* __restrict__ x,
    const float* __restrict__ W1, const float* __restrict__ bW1,
    const float* __restrict__ U1, const float* __restrict__ bU1,
    const float* __restrict__ W2, const float* __restrict__ bW2,
    const float* __restrict__ U2, const float* __restrict__ bU2,
    const float* __restrict__ lw, const float* __restrict__ lb,
    float* out, float* ws)
{
  __shared__ float red[8][8][B];
  __shared__ float outred[8][B];
  __shared__ float c1s[JPW][B], c2s[JPW][B];
  __shared__ float w1c[8], bs1[8], bs2[8];

  int* cnt   = (int*)ws;
  float* h1b = ws + 16;
  float* h2b = h1b + 2 * HB;

  const int wg   = blockIdx.x;
  const int j0   = wg * JPW;
  const int tid  = threadIdx.x;
  const int lane = tid & 63;
  const int wvu  = __builtin_amdgcn_readfirstlane(tid >> 6);
  const int kb   = wvu << 6;

  if (tid < JPW * B) { c1s[tid >> 6][lane] = 0.f; c2s[tid >> 6][lane] = 0.f; }
  if (tid < 8) {
    const int g = tid >> 1, jl = tid & 1;
    const int row = g * HID + j0 + jl;
    w1c[tid] = W1[row];
    bs1[tid] = bW1[row] + bU1[row];
    bs2[tid] = bW2[row] + bU2[row];
  }
  __syncthreads();

  const float* u1p[8]; const float* w2p[8]; const float* u2p[8];
  #pragma unroll
  for (int r = 0; r < 8; ++r) {
    const int row = (r >> 1) * HID + j0 + (r & 1);
    u1p[r] = U1 + (size_t)row * HID + kb;
    w2p[r] = W2 + (size_t)row * HID + kb;
    u2p[r] = U2 + (size_t)row * HID + kb;
  }
  const float lbv = lb[0];

  int bar = 0;
  for (int t = 0; t < TT; ++t) {
    const float* h1old = h1b + ((t + 1) & 1) * HB;
    float*       h1new = h1b + (t & 1) * HB;
    const float* h2old = h2b + ((t + 1) & 1) * HB;
    float*       h2new = h2b + (t & 1) * HB;

    {
      const float* hp = h1old + (size_t)kb * B;
      float a0=0.f,a1=0.f,a2=0.f,a3=0.f,a4=0.f,a5=0.f,a6=0.f,a7=0.f;
      #pragma unroll 8
      for (int k = 0; k < 64; ++k) {
        const float hv = hp[k * B + lane];
        a0 = fmaf(u1p[0][k], hv, a0); a1 = fmaf(u1p[1][k], hv, a1);
        a2 = fmaf(u1p[2][k], hv, a2); a3 = fmaf(u1p[3][k], hv, a3);
        a4 = fmaf(u1p[4][k], hv, a4); a5 = fmaf(u1p[5][k], hv, a5);
        a6 = fmaf(u1p[6][k], hv, a6); a7 = fmaf(u1p[7][k], hv, a7);
      }
      red[wvu][0][lane]=a0; red[wvu][1][lane]=a1; red[wvu][2][lane]=a2; red[wvu][3][lane]=a3;
      red[wvu][4][lane]=a4; red[wvu][5][lane]=a5; red[wvu][6][lane]=a6; red[wvu][7][lane]=a7;
    }
    __syncthreads();

    if (tid < JPW * B) {
      const int jl = tid >> 6, b = tid & 63;
      const float xv = (t < SEQT) ? x[(size_t)b * SEQT + t]
                                  : out[(size_t)b * TT + (t - 1)];
      float gate[4];
      #pragma unroll
      for (int g = 0; g < 4; ++g) {
        const int r = g * 2 + jl;
        float s = bs1[r] + xv * w1c[r];
        #pragma unroll
        for (int w = 0; w < 8; ++w) s += red[w][r][b];
        gate[g] = s;
      }
      const float c = gate[1] * c1s[jl][b] + gate[0] * gate[2];
      c1s[jl][b] = c;
      h1new[(size_t)(j0 + jl) * B + b] = gate[3] * tanhf(c);
    }

    ++bar;
    gbar(cnt, NWG * bar);

    if (wg == 0 && t >= 1 && t <= SEQT - 1) {
      const float* hb2 = h2old + (size_t)(wvu * 64) * B;
      const float* lwp = lw + wvu * 64;
      float p = 0.f;
      #pragma unroll 8
      for (int j = 0; j < 64; ++j) p = fmaf(lwp[j], hb2[j * B + lane], p);
      outred[wvu][lane] = p;
      __syncthreads();
      if (tid < B) {
        float o = lbv;
        #pragma unroll
        for (int s = 0; s < 8; ++s) o += outred[s][tid];
        out[(size_t)tid * TT + (t - 1)] = o;
      }
      __syncthreads();
    }

    {
      const float* h1p = h1new + (size_t)kb * B;
      const float* h2p = h2old + (size_t)kb * B;
      float s0=0.f,s1=0.f,s2=0.f,s3=0.f,s4=0.f,s5=0.f,s6=0.f,s7=0.f;
      float q0=0.f,q1=0.f,q2=0.f,q3=0.f,q4=0.f,q5=0.f,q6=0.f,q7=0.f;
      #pragma unroll 4
      for (int k = 0; k < 64; ++k) {
        const float h1v = h1p[k * B + lane];
        const float h2v = h2p[k * B + lane];
        s0 = fmaf(w2p[0][k], h1v, s0); q0 = fmaf(u2p[0][k], h2v, q0);
        s1 = fmaf(w2p[1][k], h1v, s1); q1 = fmaf(u2p[1][k], h2v, q1);
        s2 = fmaf(w2p[2][k], h1v, s2); q2 = fmaf(u2p[2][k], h2v, q2);
        s3 = fmaf(w2p[3][k], h1v, s3); q3 = fmaf(u2p[3][k], h2v, q3);
        s4 = fmaf(w2p[4][k], h1v, s4); q4 = fmaf(u2p[4][k], h2v, q4);
        s5 = fmaf(w2p[5][k], h1v, s5); q5 = fmaf(u2p[5][k], h2v, q5);
        s6 = fmaf(w2p[6][k], h1v, s6); q6 = fmaf(u2p[6][k], h2v, q6);
        s7 = fmaf(w2p[7][k], h1v, s7); q7 = fmaf(u2p[7][k], h2v, q7);
      }
      red[wvu][0][lane]=s0+q0; red[wvu][1][lane]=s1+q1;
      red[wvu][2][lane]=s2+q2; red[wvu][3][lane]=s3+q3;
      red[wvu][4][lane]=s4+q4; red[wvu][5][lane]=s5+q5;
      red[wvu][6][lane]=s6+q6; red[wvu][7][lane]=s7+q7;
    }
    __syncthreads();

    if (tid < JPW * B) {
      const int jl = tid >> 6, b = tid & 63;
      float gate[4];
      #pragma unroll
      for (int g = 0; g < 4; ++g) {
        const int r = g * 2 + jl;
        float s = bs2[r];
        #pragma unroll
        for (int w = 0; w < 8; ++w) s += red[w][r][b];
        gate[g] = s;
      }
      const float c = gate[1] * c2s[jl][b] + gate[0] * gate[2];
      c2s[jl][b] = c;
      h2new[(size_t)(j0 + jl) * B + b] = gate[3] * tanhf(c);
    }
    __syncthreads();

    if (t >= SEQT - 1) {
      ++bar;
      gbar(cnt, NWG * bar);
      if (wg == 0) {
        const float* hb2 = h2new + (size_t)(wvu * 64) * B;
        const float* lwp = lw + wvu * 64;
        float p = 0.f;
        #pragma unroll 8
        for (int j = 0; j < 64; ++j) p = fmaf(lwp[j], hb2[j * B + lane], p);
        outred[wvu][lane] = p;
        __syncthreads();
        if (tid < B) {
          float o = lbv;
          #pragma unroll
          for (int s = 0; s < 8; ++s) o += outred[s][tid];
          out[(size_t)tid * TT + t] = o;
        }
        __syncthreads();
      }
      ++bar;
      gbar(cnt, NWG * bar);
    }
  }
}

extern "C" void kernel_launch(void* const* d_in, const int* in_sizes, int n_in,
                              void* d_out, int out_size, void* d_ws, size_t ws_size,
                              hipStream_t stream) {
  (void)in_sizes; (void)n_in; (void)out_size;
  const float* x   = (const float*)d_in[0];
  const float* W1  = (const float*)d_in[1];
  const float* bW1 = (const float*)d_in[2];
  const float* U1  = (const float*)d_in[3];
  const float* bU1 = (const float*)d_in[4];
  const float* W2  = (const float*)d_in[5];
  const float* bW2 = (const float*)d_in[6];
  const float* U2  = (const float*)d_in[7];
  const float* bU2 = (const float*)d_in[8];
  const float* lw  = (const float*)d_in[9];
  const float* lb  = (const float*)d_in[10];

  float* out = (float*)d_out;
  float* ws  = (float*)d_ws;

  if (ws_size >= (size_t)WS_TOT_F * sizeof(float)) {
    const int defer = (ws_size >= WS_TOT2_F * sizeof(float)) ? 1 : 0;
    prep_ws<<<(WS_TOT_F + 255) / 256, 256, 0, stream>>>(x, U1, W2, U2, ws);
    rnn_main<<<NWG, TPB1, 0, stream>>>(W1, bW1, bU1, bW2, bU2, lw, lb, out,
                                       (int*)ws, ws + WS_H1_F, ws + WS_H2_F,
                                       ws + WS_BLOB_F, ws + WS_XT_F,
                                       ws + WS_PART_F, defer);
  } else {
    const int nzero = 16 + 4 * HID * B;
    zero_ws<<<(nzero + TPB - 1) / TPB, TPB, 0, stream>>>(ws, nzero);
    rnn_fallback<<<NWG, TPB, 0, stream>>>(x, W1, bW1, U1, bU1,
                                          W2, bW2, U2, bU2, lw, lb, out, ws);
  }
}

// Round 10
// 11867.211 us; speedup vs baseline: 1.1092x; 1.1092x over previous
//
#include <hip/hip_runtime.h>
#include <math.h>

#define HID 512
#define B 64
#define SEQT 1024
#define FUT 16
#define TT (SEQT + FUT)
#define NWG 256
#define TPB 512          // fallback path block size
#define TPB1 1024        // main kernel block size (16 waves, 4/SIMD)
#define NWAVE1 16
#define JPW 2            // hidden units owned per WG = HID/NWG
#define HB (HID * B)     // one h buffer, floats
#define BLOBF 12288      // floats per WG: 4096 (phase1) + 8192 (phase2)

typedef __attribute__((ext_vector_type(2))) float f2;   // v_pk_fma_f32 pairs

// ws float layout (main path):
//   [0..511]               barrier block (ints): slot[wg] at int wg (wg<256)
//   [512 .. +2HB)          h1 double buffer  (float4 tiles: h4[k>>2][b][k&3])
//   [.. +2HB)              h2 double buffer  (same layout)
//   [.. +NWG*BLOBF)        rearranged weight blobs (per WG)
//   [.. +SEQT*B)           xT (x transposed to [t][b])
//   [.. +SEQT*NWG*B)       deferred-output partials part[t][wg][b] (defer mode)
#define WS_H1_F   512
#define WS_H2_F   (WS_H1_F + 2 * HB)
#define WS_BLOB_F (WS_H2_F + 2 * HB)
#define WS_XT_F   (WS_BLOB_F + NWG * BLOBF)
#define WS_TOT_F  (WS_XT_F + SEQT * B)
#define WS_PART_F WS_TOT_F
#define WS_TOT2_F (WS_PART_F + (size_t)SEQT * NWG * B)

// publish device-wide WITHOUT buffer_wbl2 (r6 win: wbl2 writeback pushed h
// past the MALL -> every post-barrier read paid HBM latency).
__device__ inline void pub_store(float* p, float v) {
  __hip_atomic_store(p, v, __ATOMIC_RELAXED, __HIP_MEMORY_SCOPE_AGENT);
}

// ---- grid barrier v5: slot stores + EVERY WG polls all slots directly ------
// Rules from r2-r8: no RMW arrivals; relaxed spin loads (acquire-per-poll =
// buffer_inv per poll = L2 dead); ONE pre-spin acquire fence (inv) per WG.
__device__ inline void gbar5(int* bb, int wg, int bar) {
  __builtin_amdgcn_s_waitcnt(0);   // all waves: drain own write-through stores
  __syncthreads();
  const int tid = threadIdx.x;
  if (tid == 0) {
    __hip_atomic_store(bb + wg, bar, __ATOMIC_RELAXED, __HIP_MEMORY_SCOPE_AGENT);
    __builtin_amdgcn_fence(__ATOMIC_ACQUIRE, "agent");  // pre-spin inv, once
  }
  if (tid < 64) {                  // wave 0: poll all 256 arrival slots
    for (;;) {
      int a = __hip_atomic_load(bb + tid,       __ATOMIC_RELAXED, __HIP_MEMORY_SCOPE_AGENT);
      int b = __hip_atomic_load(bb + 64  + tid, __ATOMIC_RELAXED, __HIP_MEMORY_SCOPE_AGENT);
      int c = __hip_atomic_load(bb + 128 + tid, __ATOMIC_RELAXED, __HIP_MEMORY_SCOPE_AGENT);
      int d = __hip_atomic_load(bb + 192 + tid, __ATOMIC_RELAXED, __HIP_MEMORY_SCOPE_AGENT);
      if (__all(a >= bar && b >= bar && c >= bar && d >= bar)) break;
      __builtin_amdgcn_s_sleep(1);
    }
  }
  __syncthreads();  // h loads below stay below
}

// ---------------- prep: zero state, rearrange weights, transpose x -----------
__global__ void __launch_bounds__(256) prep_ws(
    const float* __restrict__ x,
    const float* __restrict__ U1, const float* __restrict__ W2,
    const float* __restrict__ U2, float* __restrict__ ws)
{
  const int idx = blockIdx.x * blockDim.x + threadIdx.x;
  if (idx < WS_BLOB_F) {                       // barrier block + h buffers
    ws[idx] = 0.0f;
  }
  {
    const int i2 = idx - WS_BLOB_F;
    if (i2 >= 0 && i2 < NWG * BLOBF) {
      const int wg  = i2 / BLOBF;
      const int off = i2 - wg * BLOBF;
      const int j0  = wg * JPW;
      float v;
      if (off < 4096) {                        // phase1: [k*8 + r] = U1[row(r)][k]
        const int k = off >> 3, r = off & 7;
        const int row = (r >> 1) * HID + j0 + (r & 1);
        v = U1[(size_t)row * HID + k];
      } else {                                 // phase2: [k*16 + rr]
        const int o2 = off - 4096;
        const int k = o2 >> 4, rr = o2 & 15;
        const int r = rr & 7;
        const int row = (r >> 1) * HID + j0 + (r & 1);
        v = (rr < 8) ? W2[(size_t)row * HID + k] : U2[(size_t)row * HID + k];
      }
      ws[WS_BLOB_F + i2] = v;
    }
  }
  {
    const int i3 = idx - WS_XT_F;
    if (i3 >= 0 && i3 < SEQT * B) {
      const int t = i3 >> 6, b = i3 & 63;
      ws[WS_XT_F + i3] = x[(size_t)b * SEQT + t];
    }
  }
}

// -------- persistent 2-layer LSTM: LDS weights, register-carried h1 ----------
// r10 = r8 structure (b128 weight loads, single-stage cell reduction) + ONLY
// packed-fp32 accumulation: each float4 weight quad is consumed as two f2
// halves by v_pk_fma_f32. Isolates r9's regression (b64 reads + extra syncs).
__global__ void __launch_bounds__(TPB1, 1) rnn_main(
    const float* __restrict__ W1, const float* __restrict__ bW1,
    const float* __restrict__ bU1,
    const float* __restrict__ bW2, const float* __restrict__ bU2,
    const float* __restrict__ lw, const float* __restrict__ lb,
    float* __restrict__ out,
    int* __restrict__ bb,
    float* __restrict__ h1b, float* __restrict__ h2b,
    const float* __restrict__ wbl, const float* __restrict__ xT,
    float* __restrict__ part, int defer)
{
  __shared__ float wlds[BLOBF];         // 48 KB persistent weight blob
  __shared__ float red[NWAVE1][8][B];   // per-wave partial dots, 32 KB
  __shared__ float outred[NWAVE1][B];   // output-head reduction, 4 KB
  __shared__ float c1s[JPW][B], c2s[JPW][B];
  __shared__ float pout[JPW][B];        // per-step output partial staging
  __shared__ float w1c[8], bs1[8], bs2[8], lwc[JPW];

  const int wg   = blockIdx.x;
  const int j0   = wg * JPW;
  const int tid  = threadIdx.x;
  const int lane = tid & 63;
  const int wvu  = __builtin_amdgcn_readfirstlane(tid >> 6);

  // ---- one-time: copy this WG's weight blob into LDS ----
  {
    const float4* gsrc = (const float4*)(wbl + (size_t)wg * BLOBF);
    float4* ldst = (float4*)wlds;
    #pragma unroll
    for (int i = 0; i < BLOBF / 4 / TPB1; ++i)
      ldst[i * TPB1 + tid] = gsrc[i * TPB1 + tid];
  }
  if (tid < JPW * B) { c1s[tid >> 6][lane] = 0.f; c2s[tid >> 6][lane] = 0.f; }
  if (tid < 8) {
    const int g = tid >> 1, jl = tid & 1;
    const int row = g * HID + j0 + jl;
    w1c[tid] = W1[row];
    bs1[tid] = bW1[row] + bU1[row];
    bs2[tid] = bW2[row] + bU2[row];
  }
  if (tid < JPW) lwc[tid] = lw[j0 + tid];
  __syncthreads();

  const float* wl1 = wlds + wvu * 256;          // phase1 weights, this wave
  const float* wl2 = wlds + 4096 + wvu * 512;   // phase2 weights, this wave
  const float lbv = lb[0];

  float4 H1[8], Q[8];                           // h1 carry + h2old staging
  #pragma unroll
  for (int i = 0; i < 8; ++i) H1[i] = make_float4(0.f, 0.f, 0.f, 0.f);

  int bar = 0;
  for (int t = 0; t < TT; ++t) {
    float*       h1new = h1b + (t & 1) * HB;
    const float* h2old = h2b + ((t + 1) & 1) * HB;
    float*       h2new = h2b + (t & 1) * HB;

    // prefetch x for cell-1 (teacher region)
    float xvpref = 0.f;
    if (tid < JPW * B && t < SEQT) xvpref = xT[(size_t)t * B + lane];

    // -------- phase 1: gates1 = U1 h1(t-1), h1(t-1) in H1 registers ---------
    {
      f2 a01 = {0.f, 0.f}, a23 = {0.f, 0.f}, a45 = {0.f, 0.f}, a67 = {0.f, 0.f};
      #pragma unroll
      for (int c = 0; c < 8; ++c) {             // 8 k-quads in this wave's 32-k
        const float hh[4] = {H1[c].x, H1[c].y, H1[c].z, H1[c].w};
        #pragma unroll
        for (int j = 0; j < 4; ++j) {
          const float4 wA = *(const float4*)(wl1 + c * 32 + j * 8);      // b128
          const float4 wB = *(const float4*)(wl1 + c * 32 + j * 8 + 4);  // b128
          const f2 hs = {hh[j], hh[j]};
          const f2 wA0 = {wA.x, wA.y}, wA1 = {wA.z, wA.w};
          const f2 wB0 = {wB.x, wB.y}, wB1 = {wB.z, wB.w};
          a01 = __builtin_elementwise_fma(wA0, hs, a01);
          a23 = __builtin_elementwise_fma(wA1, hs, a23);
          a45 = __builtin_elementwise_fma(wB0, hs, a45);
          a67 = __builtin_elementwise_fma(wB1, hs, a67);
        }
      }
      red[wvu][0][lane] = a01.x; red[wvu][1][lane] = a01.y;
      red[wvu][2][lane] = a23.x; red[wvu][3][lane] = a23.y;
      red[wvu][4][lane] = a45.x; red[wvu][5][lane] = a45.y;
      red[wvu][6][lane] = a67.x; red[wvu][7][lane] = a67.y;
    }
    __syncthreads();

    // cell-1 elementwise (2 j's x 64 b = 128 threads) — r8 single-stage
    if (tid < JPW * B) {
      const int jl = tid >> 6, b = tid & 63;
      const float xv = (t < SEQT) ? xvpref : out[(size_t)b * TT + (t - 1)];
      float gate[4];
      #pragma unroll
      for (int g = 0; g < 4; ++g) {
        const int r = g * 2 + jl;
        float s = bs1[r] + xv * w1c[r];
        #pragma unroll
        for (int w = 0; w < NWAVE1; ++w) s += red[w][r][b];
        gate[g] = s;
      }
      const float c = gate[1] * c1s[jl][b] + gate[0] * gate[2];
      c1s[jl][b] = c;
      const int j = j0 + jl;
      pub_store(&h1new[(size_t)(j >> 2) * (B * 4) + b * 4 + (j & 3)],
                gate[3] * tanhf(c));
    }

    ++bar;
    gbar5(bb, wg, bar);

    // non-defer mode only: duty WG computes output head inline (r7 behavior).
    if (!defer && wg == (t & 127) && t >= 1 && t <= SEQT - 1) {
      const float4* hb2 = (const float4*)h2old + (size_t)(wvu * 8) * B + lane;
      const float4* lw4 = (const float4*)lw + wvu * 8;
      float p = 0.f;
      #pragma unroll
      for (int i = 0; i < 8; ++i) {
        const float4 hv = hb2[i * B];
        const float4 wv = lw4[i];
        p = fmaf(wv.x, hv.x, p); p = fmaf(wv.y, hv.y, p);
        p = fmaf(wv.z, hv.z, p); p = fmaf(wv.w, hv.w, p);
      }
      outred[wvu][lane] = p;
      __syncthreads();
      if (tid < B) {
        float o = lbv;
        #pragma unroll
        for (int s = 0; s < NWAVE1; ++s) o += outred[s][tid];
        pub_store(&out[(size_t)tid * TT + (t - 1)], o);
      }
      __syncthreads();
    }

    // -------- phase 2: gates2 = W2 h1(t) + U2 h2(t-1) ------------------------
    // H1 <- h1(t) (kept for next step's phase 1), Q <- h2(t-1)
    {
      const float4* pp4 = (const float4*)h1new + (size_t)(wvu * 8) * B + lane;
      const float4* qq4 = (const float4*)h2old + (size_t)(wvu * 8) * B + lane;
      #pragma unroll
      for (int i = 0; i < 8; ++i) H1[i] = pp4[i * B];
      #pragma unroll
      for (int i = 0; i < 8; ++i) Q[i] = qq4[i * B];
      f2 a01 = {0.f, 0.f}, a23 = {0.f, 0.f}, a45 = {0.f, 0.f}, a67 = {0.f, 0.f};
      #pragma unroll
      for (int c = 0; c < 8; ++c) {
        const float hp_[4] = {H1[c].x, H1[c].y, H1[c].z, H1[c].w};
        const float hq_[4] = {Q[c].x, Q[c].y, Q[c].z, Q[c].w};
        #pragma unroll
        for (int j = 0; j < 4; ++j) {
          const float4 w0 = *(const float4*)(wl2 + c * 64 + j * 16);       // b128
          const float4 w1 = *(const float4*)(wl2 + c * 64 + j * 16 + 4);   // b128
          const float4 w2 = *(const float4*)(wl2 + c * 64 + j * 16 + 8);   // b128
          const float4 w3 = *(const float4*)(wl2 + c * 64 + j * 16 + 12);  // b128
          const f2 hs1 = {hp_[j], hp_[j]};
          const f2 hs2 = {hq_[j], hq_[j]};
          const f2 w0a = {w0.x, w0.y}, w0b = {w0.z, w0.w};
          const f2 w1a = {w1.x, w1.y}, w1b = {w1.z, w1.w};
          const f2 w2a = {w2.x, w2.y}, w2b = {w2.z, w2.w};
          const f2 w3a = {w3.x, w3.y}, w3b = {w3.z, w3.w};
          a01 = __builtin_elementwise_fma(w0a, hs1, a01);
          a23 = __builtin_elementwise_fma(w0b, hs1, a23);
          a45 = __builtin_elementwise_fma(w1a, hs1, a45);
          a67 = __builtin_elementwise_fma(w1b, hs1, a67);
          a01 = __builtin_elementwise_fma(w2a, hs2, a01);
          a23 = __builtin_elementwise_fma(w2b, hs2, a23);
          a45 = __builtin_elementwise_fma(w3a, hs2, a45);
          a67 = __builtin_elementwise_fma(w3b, hs2, a67);
        }
      }
      red[wvu][0][lane] = a01.x; red[wvu][1][lane] = a01.y;
      red[wvu][2][lane] = a23.x; red[wvu][3][lane] = a23.y;
      red[wvu][4][lane] = a45.x; red[wvu][5][lane] = a45.y;
      red[wvu][6][lane] = a67.x; red[wvu][7][lane] = a67.y;
    }
    __syncthreads();

    // cell-2 elementwise — r8 single-stage
    if (tid < JPW * B) {
      const int jl = tid >> 6, b = tid & 63;
      float gate[4];
      #pragma unroll
      for (int g = 0; g < 4; ++g) {
        const int r = g * 2 + jl;
        float s = bs2[r];
        #pragma unroll
        for (int w = 0; w < NWAVE1; ++w) s += red[w][r][b];
        gate[g] = s;
      }
      const float c = gate[1] * c2s[jl][b] + gate[0] * gate[2];
      c2s[jl][b] = c;
      const float h2v = gate[3] * tanhf(c);
      const int j = j0 + jl;
      pub_store(&h2new[(size_t)(j >> 2) * (B * 4) + b * 4 + (j & 3)], h2v);
      if (defer && t < SEQT) pout[jl][b] = lwc[jl] * h2v;  // output partial
    }
    __syncthreads();  // protect red[] + publish pout

    // deferred-output partial store: 64 floats/WG/step, write-through
    if (defer && t < SEQT && tid < B) {
      pub_store(&part[((size_t)t * NWG + wg) * B + tid],
                pout[0][tid] + pout[1][tid]);
    }

    // Autoregressive region: out(t) must be globally visible before phase1(t+1)
    if (t >= SEQT - 1) {
      ++bar;
      gbar5(bb, wg, bar);
      if (wg == 0) {
        const float4* hb2 = (const float4*)h2new + (size_t)(wvu * 8) * B + lane;
        const float4* lw4 = (const float4*)lw + wvu * 8;
        float p = 0.f;
        #pragma unroll
        for (int i = 0; i < 8; ++i) {
          const float4 hv = hb2[i * B];
          const float4 wv = lw4[i];
          p = fmaf(wv.x, hv.x, p); p = fmaf(wv.y, hv.y, p);
          p = fmaf(wv.z, hv.z, p); p = fmaf(wv.w, hv.w, p);
        }
        outred[wvu][lane] = p;
        __syncthreads();
        if (tid < B) {
          float o = lbv;
          #pragma unroll
          for (int s = 0; s < NWAVE1; ++s) o += outred[s][tid];
          pub_store(&out[(size_t)tid * TT + t], o);
        }
        __syncthreads();
      }
      ++bar;
      gbar5(bb, wg, bar);
    }
  }

  // ---- defer mode tail: parallel reduction of output partials (t=0..1022) --
  if (defer) {
    ++bar;
    gbar5(bb, wg, bar);   // all partial stores visible + L2 inv'd
    for (int tt = wg; tt < SEQT - 1; tt += NWG) {
      const float* pp = part + ((size_t)tt * NWG + wvu * 16) * B + lane;
      float s = 0.f;
      #pragma unroll
      for (int i = 0; i < 16; ++i) s += pp[i * B];
      outred[wvu][lane] = s;
      __syncthreads();
      if (tid < B) {
        float o = lbv;
        #pragma unroll
        for (int v = 0; v < NWAVE1; ++v) o += outred[v][tid];
        out[(size_t)tid * TT + tt] = o;
      }
      __syncthreads();
    }
  }
}

// =================== fallback path (round-0 kernel, known correct) ===========
__device__ inline void gbar(int* cnt, int target) {
  __syncthreads();
  if (threadIdx.x == 0) {
    __threadfence();
    __hip_atomic_fetch_add(cnt, 1, __ATOMIC_RELEASE, __HIP_MEMORY_SCOPE_AGENT);
    while (__hip_atomic_load(cnt, __ATOMIC_ACQUIRE, __HIP_MEMORY_SCOPE_AGENT) < target) {
      __builtin_amdgcn_s_sleep(2);
    }
  }
  __syncthreads();
}

__global__ void __launch_bounds__(TPB) zero_ws(float* ws, int n) {
  int i = blockIdx.x * blockDim.x + threadIdx.x;
  if (i < n) ws[i] = 0.0f;
}

__global__ void __launch_bounds__(TPB) rnn_fallback(
    const float* __restrict__ x,
    const float* __restrict__ W1, const float* __restrict__ bW1,
    const float* __restrict__ U1, const float* __restrict__ bU1,
    const float* __restrict__ W2, const float* __restrict__ bW2,
    const float* __restrict__ U2, const float* __restrict__ bU2,
    const float* __restrict__ lw, const float* __restrict__ lb,
    float* out, float* ws)
{
  __shared__ float red[8][8][B];
  __shared__ float outred[8][B];
  __shared__ float c1s[JPW][B], c2s[JPW][B];
  __shared__ float w1c[8], bs1[8], bs2[8];

  int* cnt   = (int*)ws;
  float* h1b = ws + 16;
  float* h2b = h1b + 2 * HB;

  const int wg   = blockIdx.x;
  const int j0   = wg * JPW;
  const int tid  = threadIdx.x;
  const int lane = tid & 63;
  const int wvu  = __builtin_amdgcn_readfirstlane(tid >> 6);
  const int kb   = wvu << 6;

  if (tid < JPW * B) { c1s[tid >> 6][lane] = 0.f; c2s[tid >> 6][lane] = 0.f; }
  if (tid < 8) {
    const int g = tid >> 1, jl = tid & 1;
    const int row = g * HID + j0 + jl;
    w1c[tid] = W1[row];
    bs1[tid] = bW1[row] + bU1[row];
    bs2[tid] = bW2[row] + bU2[row];
  }
  __syncthreads();

  const float* u1p[8]; const float* w2p[8]; const float* u2p[8];
  #pragma unroll
  for (int r = 0; r < 8; ++r) {
    const int row = (r >> 1) * HID + j0 + (r & 1);
    u1p[r] = U1 + (size_t)row * HID + kb;
    w2p[r] = W2 + (size_t)row * HID + kb;
    u2p[r] = U2 + (size_t)row * HID + kb;
  }
  const float lbv = lb[0];

  int bar = 0;
  for (int t = 0; t < TT; ++t) {
    const float* h1old = h1b + ((t + 1) & 1) * HB;
    float*       h1new = h1b + (t & 1) * HB;
    const float* h2old = h2b + ((t + 1) & 1) * HB;
    float*       h2new = h2b + (t & 1) * HB;

    {
      const float* hp = h1old + (size_t)kb * B;
      float a0=0.f,a1=0.f,a2=0.f,a3=0.f,a4=0.f,a5=0.f,a6=0.f,a7=0.f;
      #pragma unroll 8
      for (int k = 0; k < 64; ++k) {
        const float hv = hp[k * B + lane];
        a0 = fmaf(u1p[0][k], hv, a0); a1 = fmaf(u1p[1][k], hv, a1);
        a2 = fmaf(u1p[2][k], hv, a2); a3 = fmaf(u1p[3][k], hv, a3);
        a4 = fmaf(u1p[4][k], hv, a4); a5 = fmaf(u1p[5][k], hv, a5);
        a6 = fmaf(u1p[6][k], hv, a6); a7 = fmaf(u1p[7][k], hv, a7);
      }
      red[wvu][0][lane]=a0; red[wvu][1][lane]=a1; red[wvu][2][lane]=a2; red[wvu][3][lane]=a3;
      red[wvu][4][lane]=a4; red[wvu][5][lane]=a5; red[wvu][6][lane]=a6; red[wvu][7][lane]=a7;
    }
    __syncthreads();

    if (tid < JPW * B) {
      const int jl = tid >> 6, b = tid & 63;
      const float xv = (t < SEQT) ? x[(size_t)b * SEQT + t]
                                  : out[(size_t)b * TT + (t - 1)];
      float gate[4];
      #pragma unroll
      for (int g = 0; g < 4; ++g) {
        const int r = g * 2 + jl;
        float s = bs1[r] + xv * w1c[r];
        #pragma unroll
        for (int w = 0; w < 8; ++w) s += red[w][r][b];
        gate[g] = s;
      }
      const float c = gate[1] * c1s[jl][b] + gate[0] * gate[2];
      c1s[jl][b] = c;
      h1new[(size_t)(j0 + jl) * B + b] = gate[3] * tanhf(c);
    }

    ++bar;
    gbar(cnt, NWG * bar);

    if (wg == 0 && t >= 1 && t <= SEQT - 1) {
      const float* hb2 = h2old + (size_t)(wvu * 64) * B;
      const float* lwp = lw + wvu * 64;
      float p = 0.f;
      #pragma unroll 8
      for (int j = 0; j < 64; ++j) p = fmaf(lwp[j], hb2[j * B + lane], p);
      outred[wvu][lane] = p;
      __syncthreads();
      if (tid < B) {
        float o = lbv;
        #pragma unroll
        for (int s = 0; s < 8; ++s) o += outred[s][tid];
        out[(size_t)tid * TT + (t - 1)] = o;
      }
      __syncthreads();
    }

    {
      const float* h1p = h1new + (size_t)kb * B;
      const float* h2p = h2old + (size_t)kb * B;
      float s0=0.f,s1=0.f,s2=0.f,s3=0.f,s4=0.f,s5=0.f,s6=0.f,s7=0.f;
      float q0=0.f,q1=0.f,q2=0.f,q3=0.f,q4=0.f,q5=0.f,q6=0.f,q7=0.f;
      #pragma unroll 4
      for (int k = 0; k < 64; ++k) {
        const float h1v = h1p[k * B + lane];
        const float h2v = h2p[k * B + lane];
        s0 = fmaf(w2p[0][k], h1v, s0); q0 = fmaf(u2p[0][k], h2v, q0);
        s1 = fmaf(w2p[1][k], h1v, s1); q1 = fmaf(u2p[1][k], h2v, q1);
        s2 = fmaf(w2p[2][k], h1v, s2); q2 = fmaf(u2p[2][k], h2v, q2);
        s3 = fmaf(w2p[3][k], h1v, s3); q3 = fmaf(u2p[3][k], h2v, q3);
        s4 = fmaf(w2p[4][k], h1v, s4); q4 = fmaf(u2p[4][k], h2v, q4);
        s5 = fmaf(w2p[5][k], h1v, s5); q5 = fmaf(u2p[5][k], h2v, q5);
        s6 = fmaf(w2p[6][k], h1v, s6); q6 = fmaf(u2p[6][k], h2v, q6);
        s7 = fmaf(w2p[7][k], h1v, s7); q7 = fmaf(u2p[7][k], h2v, q7);
      }
      red[wvu][0][lane]=s0+q0; red[wvu][1][lane]=s1+q1;
      red[wvu][2][lane]=s2+q2; red[wvu][3][lane]=s3+q3;
      red[wvu][4][lane]=s4+q4; red[wvu][5][lane]=s5+q5;
      red[wvu][6][lane]=s6+q6; red[wvu][7][lane]=s7+q7;
    }
    __syncthreads();

    if (tid < JPW * B) {
      const int jl = tid >> 6, b = tid & 63;
      float gate[4];
      #pragma unroll
      for (int g = 0; g < 4; ++g) {
        const int r = g * 2 + jl;
        float s = bs2[r];
        #pragma unroll
        for (int w = 0; w < 8; ++w) s += red[w][r][b];
        gate[g] = s;
      }
      const float c = gate[1] * c2s[jl][b] + gate[0] * gate[2];
      c2s[jl][b] = c;
      h2new[(size_t)(j0 + jl) * B + b] = gate[3] * tanhf(c);
    }
    __syncthreads();

    if (t >= SEQT - 1) {
      ++bar;
      gbar(cnt, NWG * bar);
      if (wg == 0) {
        const float* hb2 = h2new + (size_t)(wvu * 64) * B;
        const float* lwp = lw + wvu * 64;
        float p = 0.f;
        #pragma unroll 8
        for (int j = 0; j < 64; ++j) p = fmaf(lwp[j], hb2[j * B + lane], p);
        outred[wvu][lane] = p;
        __syncthreads();
        if (tid < B) {
          float o = lbv;
          #pragma unroll
          for (int s = 0; s < 8; ++s) o += outred[s][tid];
          out[(size_t)tid * TT + t] = o;
        }
        __syncthreads();
      }
      ++bar;
      gbar(cnt, NWG * bar);
    }
  }
}

extern "C" void kernel_launch(void* const* d_in, const int* in_sizes, int n_in,
                              void* d_out, int out_size, void* d_ws, size_t ws_size,
                              hipStream_t stream) {
  (void)in_sizes; (void)n_in; (void)out_size;
  const float* x   = (const float*)d_in[0];
  const float* W1  = (const float*)d_in[1];
  const float* bW1 = (const float*)d_in[2];
  const float* U1  = (const float*)d_in[3];
  const float* bU1 = (const float*)d_in[4];
  const float* W2  = (const float*)d_in[5];
  const float* bW2 = (const float*)d_in[6];
  const float* U2  = (const float*)d_in[7];
  const float* bU2 = (const float*)d_in[8];
  const float* lw  = (const float*)d_in[9];
  const float* lb  = (const float*)d_in[10];

  float* out = (float*)d_out;
  float* ws  = (float*)d_ws;

  if (ws_size >= (size_t)WS_TOT_F * sizeof(float)) {
    const int defer = (ws_size >= WS_TOT2_F * sizeof(float)) ? 1 : 0;
    prep_ws<<<(WS_TOT_F + 255) / 256, 256, 0, stream>>>(x, U1, W2, U2, ws);
    rnn_main<<<NWG, TPB1, 0, stream>>>(W1, bW1, bU1, bW2, bU2, lw, lb, out,
                                       (int*)ws, ws + WS_H1_F, ws + WS_H2_F,
                                       ws + WS_BLOB_F, ws + WS_XT_F,
                                       ws + WS_PART_F, defer);
  } else {
    const int nzero = 16 + 4 * HID * B;
    zero_ws<<<(nzero + TPB - 1) / TPB, TPB, 0, stream>>>(ws, nzero);
    rnn_fallback<<<NWG, TPB, 0, stream>>>(x, W1, bW1, U1, bU1,
                                          W2, bW2, U2, bU2, lw, lb, out, ws);
  }
}